// Round 6
// baseline (1985.828 us; speedup 1.0000x reference)
//
#include <hip/hip_runtime.h>
#include <hip/hip_bf16.h>

#define B_    8
#define N_    4096
#define D_    64
#define NP_   1024
#define K_    32
#define NC_   212
#define NCP_  216
#define CO_   128
#define FPS_T 512

// f32 ops with guaranteed IEEE rounding, no FMA contraction — must match numpy f32 bit-exactly.
__device__ __forceinline__ float f32add(float a, float b) { return __fadd_rn(a, b); }
__device__ __forceinline__ float f32sub(float a, float b) { return __fsub_rn(a, b); }
__device__ __forceinline__ float f32mul(float a, float b) { return __fmul_rn(a, b); }

// ---------------------------------------------------------------------------
// Kernel 1: farthest point sampling, one block per batch.
// All distance math in f32 with the numpy reference's exact op order:
// nd = ((dx*dx + dy*dy) + dz*dz) UNFUSED (elementwise **2 then serial sum —
// no contraction in the reference), dist = min(dist, nd), argmax first-max.
// Verified bit-matching (output 0 passed rounds 4 & 5).
// ---------------------------------------------------------------------------
__global__ __launch_bounds__(FPS_T) void fps_kernel(
    const float* __restrict__ xyz,
    int* __restrict__ fpsIdx, float* __restrict__ out0) {
    int b = blockIdx.x;
    const float* P = xyz + (size_t)b * N_ * 3;
    __shared__ float X[N_], Y[N_], Z[N_];
    __shared__ int   hist[NP_];
    __shared__ float redV[2][FPS_T / 64];
    __shared__ int   redI[2][FPS_T / 64];
    int tid = threadIdx.x;
    for (int i = tid; i < N_; i += FPS_T) {
        X[i] = P[i * 3 + 0];
        Y[i] = P[i * 3 + 1];
        Z[i] = P[i * 3 + 2];
    }
    if (tid == 0) hist[0] = 0;
    __syncthreads();

    const int PPT = N_ / FPS_T;  // 8
    float px[PPT], py[PPT], pz[PPT], dist[PPT];
#pragma unroll
    for (int c = 0; c < PPT; c++) {
        int j = tid + FPS_T * c;
        px[c] = X[j]; py[c] = Y[j]; pz[c] = Z[j];
        dist[c] = 1e10f;
    }
    int last = 0;
    for (int it = 1; it < NP_; ++it) {
        float lx = X[last], ly = Y[last], lz = Z[last];
        float best = -1.0f; int bidx = 0;
#pragma unroll
        for (int c = 0; c < PPT; c++) {
            float dx = f32sub(px[c], lx), dy = f32sub(py[c], ly), dz = f32sub(pz[c], lz);
            float nd = f32add(f32add(f32mul(dx, dx), f32mul(dy, dy)), f32mul(dz, dz));
            float d  = fminf(dist[c], nd);
            dist[c] = d;
            if (d > best) { best = d; bidx = tid + FPS_T * c; }   // ties: lowest j (c ascending)
        }
        // wave-level argmax (64 lanes), tie -> lowest index (np.argmax semantics)
#pragma unroll
        for (int off = 1; off < 64; off <<= 1) {
            float ov = __shfl_xor(best, off);
            int   oi = __shfl_xor(bidx, off);
            if (ov > best || (ov == best && oi < bidx)) { best = ov; bidx = oi; }
        }
        int par = it & 1;
        if ((tid & 63) == 0) { redV[par][tid >> 6] = best; redI[par][tid >> 6] = bidx; }
        __syncthreads();  // single barrier per iter; parity double-buffer makes it safe
        float bv = redV[par][0]; int bi = redI[par][0];
#pragma unroll
        for (int w = 1; w < FPS_T / 64; w++) {
            float ov = redV[par][w]; int oi = redI[par][w];
            if (ov > bv || (ov == bv && oi < bi)) { bv = ov; bi = oi; }
        }
        last = bi;
        if (tid == 0) hist[it] = last;
    }
    __syncthreads();
    for (int i = tid; i < NP_; i += FPS_T) {
        int j = hist[i];
        fpsIdx[b * NP_ + i] = j;
        size_t o = (size_t)(b * NP_ + i) * 3;
        out0[o + 0] = X[j]; out0[o + 1] = Y[j]; out0[o + 2] = Z[j];
    }
}

// ---------------------------------------------------------------------------
// Kernel 2: fused ball-query + feature_enhance + hetero_attention.
// One block (256 threads) per query point. f32 in/out.
// Ball query d2 = (sq + sxj) - 2*dot, where sq/sxj are UNFUSED serial sums
// (elementwise **2 then sum) and dot is an ASCENDING FMA CHAIN — matching
// the einsum contraction as compiled by numpy/BLAS (rank-1 fma updates).
// nfn columns: 0-2 gn*fd | 3-5 g | 6-8 g-gn | 9 dg | 10-73 fn | 74-76 gd |
//              77-140 f | 141-143 g | 144-207 f-fn | 208-210 g-gd | 211 df
// ---------------------------------------------------------------------------
__global__ __launch_bounds__(256) void fused_kernel(
    const float* __restrict__ feat, const float* __restrict__ xyz,
    const float* __restrict__ newxyz, const int* __restrict__ fpsIdx,
    const float* __restrict__ A, const float* __restrict__ W1,
    const float* __restrict__ B1, float* __restrict__ out1) {
    int q = blockIdx.x;
    int b = q >> 10, n = q & (NP_ - 1);
    int tid = threadIdx.x;
    __shared__ float sNF[K_][NCP_];
    __shared__ float sF[68];       // f(64) ++ g(3)
    __shared__ float sFD[K_];
    __shared__ float sGD[3];
    __shared__ float sGsum[3];
    __shared__ float sPool[NC_];
    __shared__ int   sNb[K_];
    __shared__ int   sCnt;

    // f gather (strided scalar loads from (B,64,N) layout) + g
    if (tid < D_) sF[tid] = feat[((size_t)b * D_ + tid) * N_ + fpsIdx[q]];
    if (tid >= D_ && tid < D_ + 3) sF[tid] = newxyz[q * 3 + (tid - D_)];

    // wave 0: ball query (first 32 in-index-order within radius), exact-f32.
    if (tid < 64) {
        int lane = tid;
        if (lane < K_) sNb[lane] = N_ - 1;   // empty-ball fallback == reference's min(N, N-1)
        const float* P = xyz + (size_t)b * N_ * 3;
        float qx = newxyz[q * 3 + 0];
        float qy = newxyz[q * 3 + 1];
        float qz = newxyz[q * 3 + 2];
        float sq = f32add(f32add(f32mul(qx, qx), f32mul(qy, qy)), f32mul(qz, qz));
        const float R2 = (float)(0.2 * 0.2);   // == f32 nearest to 0.04 — promotion-safe
        int count = 0;
        for (int base = 0; base < N_ && count < K_; base += 64) {
            int j = base + lane;
            float x = P[j * 3 + 0];
            float y = P[j * 3 + 1];
            float z = P[j * 3 + 2];
            float sxj = f32add(f32add(f32mul(x, x), f32mul(y, y)), f32mul(z, z));
            // einsum dot: ascending-c FMA chain (c=0 product rounded once, then fma)
            float dot = __fmaf_rn(qz, z, __fmaf_rn(qy, y, __fmul_rn(qx, x)));
            float d2  = f32sub(f32add(sq, sxj), f32mul(2.0f, dot));
            bool in = (d2 <= R2);
            unsigned long long m = __ballot(in);
            if (in) {
                int pos = count + __popcll(m & ((1ull << lane) - 1ull));
                if (pos < K_) sNb[pos] = j;
            }
            count += __popcll(m);
        }
        if (lane == 0) sCnt = (count < K_) ? count : K_;
    }
    __syncthreads();
    int cnt = sCnt;

    // fn -> cols 10..73 (strided gather from (B,64,N)); raw gn -> cols 0..2
    {
        int k = tid >> 3, l = tid & 7;
        int j = (k < cnt || cnt == 0) ? sNb[k] : sNb[0];
        const float* src = feat + (size_t)b * D_ * N_ + j;
#pragma unroll
        for (int dd = 0; dd < 8; dd++) {
            int d = l * 8 + dd;
            sNF[k][10 + d] = src[(size_t)d * N_];
        }
    }
    if (tid < 96) {
        int k = tid / 3, c = tid % 3;
        int j = (k < cnt || cnt == 0) ? sNb[k] : sNb[0];
        sNF[k][c] = xyz[((size_t)b * N_ + j) * 3 + c];
    }
    __syncthreads();

    // fdist per neighbor: 8-thread groups
    {
        int k = tid >> 3, ds = (tid & 7) * 8;
        float s = 0.f;
#pragma unroll
        for (int j = 0; j < 8; j++) s += fabsf(sF[ds + j] - sNF[k][10 + ds + j]);
        s += __shfl_xor(s, 1); s += __shfl_xor(s, 2); s += __shfl_xor(s, 4);
        if ((tid & 7) == 0) sFD[k] = __expf(-s * (1.0f / 64.0f));
    }
    __syncthreads();

    // scale gn, fill pg, pg1
    if (tid < 96) {
        int k = tid / 3, c = tid % 3;
        float v = sNF[k][c] * sFD[k];
        float g = sF[D_ + c];
        sNF[k][c]     = v;
        sNF[k][3 + c] = g;
        sNF[k][6 + c] = g - v;
    }
    __syncthreads();

    if (tid < 3) { float s = 0.f; for (int k = 0; k < K_; k++) s += sNF[k][tid]; sGsum[tid] = s; }
    if (tid >= 64 && tid < 96) {
        int k = tid - 64;
        float a0 = sNF[k][6], a1 = sNF[k][7], a2 = sNF[k][8];
        sNF[k][9] = sqrtf(a0 * a0 + a1 * a1 + a2 * a2);   // dg
    }
    __syncthreads();

    if (tid == 0) {
        float m0 = sGsum[0] * (1.f / K_), m1 = sGsum[1] * (1.f / K_), m2 = sGsum[2] * (1.f / K_);
        float mm = fmaxf(m0, fmaxf(m1, m2));
        float e0 = __expf(m0 - mm), e1 = __expf(m1 - mm), e2 = __expf(m2 - mm);
        float inv = 1.f / (e0 + e1 + e2);
        float g0 = sF[D_], g1 = sF[D_ + 1], g2 = sF[D_ + 2];
        float gm = fmaxf(g0, fmaxf(g1, g2));
        float f0 = __expf(g0 - gm), f1 = __expf(g1 - gm), f2 = __expf(g2 - gm);
        float inv2 = 1.f / (f0 + f1 + f2);
        sGD[0] = fabsf(e0 * inv - f0 * inv2);
        sGD[1] = fabsf(e1 * inv - f1 * inv2);
        sGD[2] = fabsf(e2 * inv - f2 * inv2);
    }
    __syncthreads();

    // pf (77..143), pf1 (144..210), gd (74..76)
    for (int x = tid; x < K_ * 67; x += 256) {
        int k = x / 67, c = x % 67;
        float pf  = sF[c];
        float fnx = (c < D_) ? sNF[k][10 + c] : sGD[c - D_];
        sNF[k][77 + c]  = pf;
        sNF[k][144 + c] = pf - fnx;
        if (c >= D_) sNF[k][74 + (c - D_)] = fnx;
    }
    __syncthreads();

    // df (col 211): 8-thread groups over the 67 pf1 entries
    {
        int k = tid >> 3, l = tid & 7;
        float s = 0.f;
        for (int c = l; c < 67; c += 8) { float v = sNF[k][144 + c]; s += v * v; }
        s += __shfl_xor(s, 1); s += __shfl_xor(s, 2); s += __shfl_xor(s, 4);
        if (l == 0) sNF[k][211] = sqrtf(s);
    }
    __syncthreads();

    // e = leaky(nfn @ a); softmax over k; pooled
    if (tid < NC_) {
        float acc[K_];
#pragma unroll
        for (int k = 0; k < K_; k++) acc[k] = 0.f;
        const float* Ar = A + tid;
        for (int c = 0; c < NC_; c += 4) {
            float a0 = Ar[(size_t)(c + 0) * NC_];
            float a1 = Ar[(size_t)(c + 1) * NC_];
            float a2 = Ar[(size_t)(c + 2) * NC_];
            float a3 = Ar[(size_t)(c + 3) * NC_];
#pragma unroll
            for (int k = 0; k < K_; k++) {
                float4 nv = *(const float4*)&sNF[k][c];
                acc[k] = fmaf(nv.w, a3, fmaf(nv.z, a2, fmaf(nv.y, a1, fmaf(nv.x, a0, acc[k]))));
            }
        }
        float m = -1e30f;
#pragma unroll
        for (int k = 0; k < K_; k++) {
            float v = acc[k];
            v = (v > 0.f) ? v : 0.2f * v;   // leaky_relu(., 0.2)
            acc[k] = v;
            m = fmaxf(m, v);
        }
        float ssum = 0.f;
#pragma unroll
        for (int k = 0; k < K_; k++) { float e = __expf(acc[k] - m); acc[k] = e; ssum += e; }
        float inv = 1.f / ssum;
        float p = 0.f;
#pragma unroll
        for (int k = 0; k < K_; k++) p += acc[k] * sNF[k][tid];
        sPool[tid] = p * inv;
    }
    __syncthreads();

    // out = pooled @ w1^T + b1, stored transposed (B, 128, 1024) as f32
    if (tid < CO_) {
        const float* w = W1 + (size_t)tid * NC_;
        float accO = 0.f;
        for (int c = 0; c < NC_; c += 4) {
            float4 wv = *(const float4*)(w + c);
            accO += wv.x * sPool[c] + wv.y * sPool[c + 1] + wv.z * sPool[c + 2] + wv.w * sPool[c + 3];
        }
        accO += B1[tid];
        out1[((size_t)b * CO_ + tid) * NP_ + n] = accO;
    }
}

// ---------------------------------------------------------------------------
extern "C" void kernel_launch(void* const* d_in, const int* in_sizes, int n_in,
                              void* d_out, int out_size, void* d_ws, size_t ws_size,
                              hipStream_t stream) {
    (void)in_sizes; (void)n_in; (void)out_size; (void)ws_size;
    const float* xyz      = (const float*)d_in[0];
    const float* features = (const float*)d_in[1];
    const float* A        = (const float*)d_in[2];
    const float* W1       = (const float*)d_in[3];
    const float* B1       = (const float*)d_in[4];
    float* out0 = (float*)d_out;                     // new_xyz (B,1024,3) f32
    float* out1 = out0 + (size_t)B_ * NP_ * 3;       // features (B,128,1024) f32

    int* fpsIdx = (int*)d_ws;                        // B*NP ints (32 KB)

    fps_kernel<<<dim3(B_), dim3(FPS_T), 0, stream>>>(xyz, fpsIdx, out0);
    fused_kernel<<<dim3(B_ * NP_), dim3(256), 0, stream>>>(features, xyz, out0, fpsIdx,
                                                           A, W1, B1, out1);
}

// Round 7
// 1839.044 us; speedup vs baseline: 1.0798x; 1.0798x over previous
//
#include <hip/hip_runtime.h>
#include <hip/hip_bf16.h>

#define B_    8
#define N_    4096
#define D_    64
#define NP_   1024
#define K_    32
#define NC_   212
#define NCP_  216
#define CO_   128
#define FPS_T 512

// f32 ops with guaranteed IEEE rounding, no FMA contraction — must match numpy f32 bit-exactly.
__device__ __forceinline__ float f32add(float a, float b) { return __fadd_rn(a, b); }
__device__ __forceinline__ float f32sub(float a, float b) { return __fsub_rn(a, b); }
__device__ __forceinline__ float f32mul(float a, float b) { return __fmul_rn(a, b); }

// Wave64 argmax via DPP directional reduce (row_shr 1/2/4/8, row_bcast 15/31).
// Merge = (max value, min index on tie) — associative/commutative, equals
// np.argmax first-max. Result broadcast from lane 63. All VALU-speed (no LDS).
__device__ __forceinline__ void waveArgmaxDpp(float& best, int& bidx) {
#define AMAX_STEP(CTRL)                                                                     \
    {                                                                                       \
        int _v = __builtin_amdgcn_update_dpp(__float_as_int(best), __float_as_int(best),    \
                                             (CTRL), 0xf, 0xf, false);                      \
        int _i = __builtin_amdgcn_update_dpp(bidx, bidx, (CTRL), 0xf, 0xf, false);          \
        float _f = __int_as_float(_v);                                                      \
        if (_f > best || (_f == best && _i < bidx)) { best = _f; bidx = _i; }               \
    }
    AMAX_STEP(0x111);  // row_shr:1
    AMAX_STEP(0x112);  // row_shr:2
    AMAX_STEP(0x114);  // row_shr:4
    AMAX_STEP(0x118);  // row_shr:8
    AMAX_STEP(0x142);  // row_bcast:15
    AMAX_STEP(0x143);  // row_bcast:31
#undef AMAX_STEP
    best = __int_as_float(__builtin_amdgcn_readlane(__float_as_int(best), 63));
    bidx = __builtin_amdgcn_readlane(bidx, 63);
}

// ---------------------------------------------------------------------------
// Kernel 1: farthest point sampling, one block per batch.
// Distance math bit-matches numpy-f32 (unfused, reference op order) — verified
// passing (rounds 4-6). Argmax reduce now DPP-based (was ds_bpermute butterfly).
// ---------------------------------------------------------------------------
__global__ __launch_bounds__(FPS_T) void fps_kernel(
    const float* __restrict__ xyz,
    int* __restrict__ fpsIdx, float* __restrict__ out0) {
    int b = blockIdx.x;
    const float* P = xyz + (size_t)b * N_ * 3;
    __shared__ float X[N_], Y[N_], Z[N_];
    __shared__ int   hist[NP_];
    __shared__ float redV[2][FPS_T / 64];
    __shared__ int   redI[2][FPS_T / 64];
    int tid = threadIdx.x;
    for (int i = tid; i < N_; i += FPS_T) {
        X[i] = P[i * 3 + 0];
        Y[i] = P[i * 3 + 1];
        Z[i] = P[i * 3 + 2];
    }
    if (tid == 0) hist[0] = 0;
    __syncthreads();

    const int PPT = N_ / FPS_T;  // 8
    float px[PPT], py[PPT], pz[PPT], dist[PPT];
#pragma unroll
    for (int c = 0; c < PPT; c++) {
        int j = tid + FPS_T * c;
        px[c] = X[j]; py[c] = Y[j]; pz[c] = Z[j];
        dist[c] = 1e10f;
    }
    int last = 0;
    for (int it = 1; it < NP_; ++it) {
        float lx = X[last], ly = Y[last], lz = Z[last];
        float best = -1.0f; int bidx = 0;
#pragma unroll
        for (int c = 0; c < PPT; c++) {
            float dx = f32sub(px[c], lx), dy = f32sub(py[c], ly), dz = f32sub(pz[c], lz);
            float nd = f32add(f32add(f32mul(dx, dx), f32mul(dy, dy)), f32mul(dz, dz));
            float d  = fminf(dist[c], nd);
            dist[c] = d;
            if (d > best) { best = d; bidx = tid + FPS_T * c; }   // ties: lowest j (c ascending)
        }
        waveArgmaxDpp(best, bidx);   // wave result in all lanes
        int par = it & 1;
        if ((tid & 63) == 0) { redV[par][tid >> 6] = best; redI[par][tid >> 6] = bidx; }
        __syncthreads();  // single barrier per iter; parity double-buffer makes it safe
        float bv = redV[par][0]; int bi = redI[par][0];
#pragma unroll
        for (int w = 1; w < FPS_T / 64; w++) {
            float ov = redV[par][w]; int oi = redI[par][w];
            if (ov > bv || (ov == bv && oi < bi)) { bv = ov; bi = oi; }
        }
        last = bi;
        if (tid == 0) hist[it] = last;
    }
    __syncthreads();
    for (int i = tid; i < NP_; i += FPS_T) {
        int j = hist[i];
        fpsIdx[b * NP_ + i] = j;
        size_t o = (size_t)(b * NP_ + i) * 3;
        out0[o + 0] = X[j]; out0[o + 1] = Y[j]; out0[o + 2] = Z[j];
    }
}

// ---------------------------------------------------------------------------
// Kernel 2: fused ball-query + feature_enhance + hetero_attention (UNCHANGED
// from the passing round-6 kernel — isolating the FPS delta).
// ---------------------------------------------------------------------------
__global__ __launch_bounds__(256) void fused_kernel(
    const float* __restrict__ feat, const float* __restrict__ xyz,
    const float* __restrict__ newxyz, const int* __restrict__ fpsIdx,
    const float* __restrict__ A, const float* __restrict__ W1,
    const float* __restrict__ B1, float* __restrict__ out1) {
    int q = blockIdx.x;
    int b = q >> 10, n = q & (NP_ - 1);
    int tid = threadIdx.x;
    __shared__ float sNF[K_][NCP_];
    __shared__ float sF[68];       // f(64) ++ g(3)
    __shared__ float sFD[K_];
    __shared__ float sGD[3];
    __shared__ float sGsum[3];
    __shared__ float sPool[NC_];
    __shared__ int   sNb[K_];
    __shared__ int   sCnt;

    // f gather (strided scalar loads from (B,64,N) layout) + g
    if (tid < D_) sF[tid] = feat[((size_t)b * D_ + tid) * N_ + fpsIdx[q]];
    if (tid >= D_ && tid < D_ + 3) sF[tid] = newxyz[q * 3 + (tid - D_)];

    // wave 0: ball query (first 32 in-index-order within radius), exact-f32.
    if (tid < 64) {
        int lane = tid;
        if (lane < K_) sNb[lane] = N_ - 1;   // empty-ball fallback == reference's min(N, N-1)
        const float* P = xyz + (size_t)b * N_ * 3;
        float qx = newxyz[q * 3 + 0];
        float qy = newxyz[q * 3 + 1];
        float qz = newxyz[q * 3 + 2];
        float sq = f32add(f32add(f32mul(qx, qx), f32mul(qy, qy)), f32mul(qz, qz));
        const float R2 = (float)(0.2 * 0.2);
        int count = 0;
        for (int base = 0; base < N_ && count < K_; base += 64) {
            int j = base + lane;
            float x = P[j * 3 + 0];
            float y = P[j * 3 + 1];
            float z = P[j * 3 + 2];
            float sxj = f32add(f32add(f32mul(x, x), f32mul(y, y)), f32mul(z, z));
            // einsum dot: ascending-c FMA chain (c=0 product rounded once, then fma)
            float dot = __fmaf_rn(qz, z, __fmaf_rn(qy, y, __fmul_rn(qx, x)));
            float d2  = f32sub(f32add(sq, sxj), f32mul(2.0f, dot));
            bool in = (d2 <= R2);
            unsigned long long m = __ballot(in);
            if (in) {
                int pos = count + __popcll(m & ((1ull << lane) - 1ull));
                if (pos < K_) sNb[pos] = j;
            }
            count += __popcll(m);
        }
        if (lane == 0) sCnt = (count < K_) ? count : K_;
    }
    __syncthreads();
    int cnt = sCnt;

    // fn -> cols 10..73 (strided gather from (B,64,N)); raw gn -> cols 0..2
    {
        int k = tid >> 3, l = tid & 7;
        int j = (k < cnt || cnt == 0) ? sNb[k] : sNb[0];
        const float* src = feat + (size_t)b * D_ * N_ + j;
#pragma unroll
        for (int dd = 0; dd < 8; dd++) {
            int d = l * 8 + dd;
            sNF[k][10 + d] = src[(size_t)d * N_];
        }
    }
    if (tid < 96) {
        int k = tid / 3, c = tid % 3;
        int j = (k < cnt || cnt == 0) ? sNb[k] : sNb[0];
        sNF[k][c] = xyz[((size_t)b * N_ + j) * 3 + c];
    }
    __syncthreads();

    // fdist per neighbor: 8-thread groups
    {
        int k = tid >> 3, ds = (tid & 7) * 8;
        float s = 0.f;
#pragma unroll
        for (int j = 0; j < 8; j++) s += fabsf(sF[ds + j] - sNF[k][10 + ds + j]);
        s += __shfl_xor(s, 1); s += __shfl_xor(s, 2); s += __shfl_xor(s, 4);
        if ((tid & 7) == 0) sFD[k] = __expf(-s * (1.0f / 64.0f));
    }
    __syncthreads();

    // scale gn, fill pg, pg1
    if (tid < 96) {
        int k = tid / 3, c = tid % 3;
        float v = sNF[k][c] * sFD[k];
        float g = sF[D_ + c];
        sNF[k][c]     = v;
        sNF[k][3 + c] = g;
        sNF[k][6 + c] = g - v;
    }
    __syncthreads();

    if (tid < 3) { float s = 0.f; for (int k = 0; k < K_; k++) s += sNF[k][tid]; sGsum[tid] = s; }
    if (tid >= 64 && tid < 96) {
        int k = tid - 64;
        float a0 = sNF[k][6], a1 = sNF[k][7], a2 = sNF[k][8];
        sNF[k][9] = sqrtf(a0 * a0 + a1 * a1 + a2 * a2);   // dg
    }
    __syncthreads();

    if (tid == 0) {
        float m0 = sGsum[0] * (1.f / K_), m1 = sGsum[1] * (1.f / K_), m2 = sGsum[2] * (1.f / K_);
        float mm = fmaxf(m0, fmaxf(m1, m2));
        float e0 = __expf(m0 - mm), e1 = __expf(m1 - mm), e2 = __expf(m2 - mm);
        float inv = 1.f / (e0 + e1 + e2);
        float g0 = sF[D_], g1 = sF[D_ + 1], g2 = sF[D_ + 2];
        float gm = fmaxf(g0, fmaxf(g1, g2));
        float f0 = __expf(g0 - gm), f1 = __expf(g1 - gm), f2 = __expf(g2 - gm);
        float inv2 = 1.f / (f0 + f1 + f2);
        sGD[0] = fabsf(e0 * inv - f0 * inv2);
        sGD[1] = fabsf(e1 * inv - f1 * inv2);
        sGD[2] = fabsf(e2 * inv - f2 * inv2);
    }
    __syncthreads();

    // pf (77..143), pf1 (144..210), gd (74..76)
    for (int x = tid; x < K_ * 67; x += 256) {
        int k = x / 67, c = x % 67;
        float pf  = sF[c];
        float fnx = (c < D_) ? sNF[k][10 + c] : sGD[c - D_];
        sNF[k][77 + c]  = pf;
        sNF[k][144 + c] = pf - fnx;
        if (c >= D_) sNF[k][74 + (c - D_)] = fnx;
    }
    __syncthreads();

    // df (col 211): 8-thread groups over the 67 pf1 entries
    {
        int k = tid >> 3, l = tid & 7;
        float s = 0.f;
        for (int c = l; c < 67; c += 8) { float v = sNF[k][144 + c]; s += v * v; }
        s += __shfl_xor(s, 1); s += __shfl_xor(s, 2); s += __shfl_xor(s, 4);
        if (l == 0) sNF[k][211] = sqrtf(s);
    }
    __syncthreads();

    // e = leaky(nfn @ a); softmax over k; pooled
    if (tid < NC_) {
        float acc[K_];
#pragma unroll
        for (int k = 0; k < K_; k++) acc[k] = 0.f;
        const float* Ar = A + tid;
        for (int c = 0; c < NC_; c += 4) {
            float a0 = Ar[(size_t)(c + 0) * NC_];
            float a1 = Ar[(size_t)(c + 1) * NC_];
            float a2 = Ar[(size_t)(c + 2) * NC_];
            float a3 = Ar[(size_t)(c + 3) * NC_];
#pragma unroll
            for (int k = 0; k < K_; k++) {
                float4 nv = *(const float4*)&sNF[k][c];
                acc[k] = fmaf(nv.w, a3, fmaf(nv.z, a2, fmaf(nv.y, a1, fmaf(nv.x, a0, acc[k]))));
            }
        }
        float m = -1e30f;
#pragma unroll
        for (int k = 0; k < K_; k++) {
            float v = acc[k];
            v = (v > 0.f) ? v : 0.2f * v;   // leaky_relu(., 0.2)
            acc[k] = v;
            m = fmaxf(m, v);
        }
        float ssum = 0.f;
#pragma unroll
        for (int k = 0; k < K_; k++) { float e = __expf(acc[k] - m); acc[k] = e; ssum += e; }
        float inv = 1.f / ssum;
        float p = 0.f;
#pragma unroll
        for (int k = 0; k < K_; k++) p += acc[k] * sNF[k][tid];
        sPool[tid] = p * inv;
    }
    __syncthreads();

    // out = pooled @ w1^T + b1, stored transposed (B, 128, 1024) as f32
    if (tid < CO_) {
        const float* w = W1 + (size_t)tid * NC_;
        float accO = 0.f;
        for (int c = 0; c < NC_; c += 4) {
            float4 wv = *(const float4*)(w + c);
            accO += wv.x * sPool[c] + wv.y * sPool[c + 1] + wv.z * sPool[c + 2] + wv.w * sPool[c + 3];
        }
        accO += B1[tid];
        out1[((size_t)b * CO_ + tid) * NP_ + n] = accO;
    }
}

// ---------------------------------------------------------------------------
extern "C" void kernel_launch(void* const* d_in, const int* in_sizes, int n_in,
                              void* d_out, int out_size, void* d_ws, size_t ws_size,
                              hipStream_t stream) {
    (void)in_sizes; (void)n_in; (void)out_size; (void)ws_size;
    const float* xyz      = (const float*)d_in[0];
    const float* features = (const float*)d_in[1];
    const float* A        = (const float*)d_in[2];
    const float* W1       = (const float*)d_in[3];
    const float* B1       = (const float*)d_in[4];
    float* out0 = (float*)d_out;                     // new_xyz (B,1024,3) f32
    float* out1 = out0 + (size_t)B_ * NP_ * 3;       // features (B,128,1024) f32

    int* fpsIdx = (int*)d_ws;                        // B*NP ints (32 KB)

    fps_kernel<<<dim3(B_), dim3(FPS_T), 0, stream>>>(xyz, fpsIdx, out0);
    fused_kernel<<<dim3(B_ * NP_), dim3(256), 0, stream>>>(features, xyz, out0, fpsIdx,
                                                           A, W1, B1, out1);
}

// Round 8
// 1296.336 us; speedup vs baseline: 1.5319x; 1.4186x over previous
//
#include <hip/hip_runtime.h>
#include <hip/hip_bf16.h>

#define B_    8
#define N_    4096
#define D_    64
#define NP_   1024
#define K_    32
#define NC_   212
#define CO_   128
#define FPS_T 256
#define SVW   72    // sV row width: [gnf(3), dg(1), fn(64), df(1), pad0(3)]

// f32 ops with guaranteed IEEE rounding, no FMA contraction — must match numpy f32 bit-exactly.
__device__ __forceinline__ float f32add(float a, float b) { return __fadd_rn(a, b); }
__device__ __forceinline__ float f32sub(float a, float b) { return __fsub_rn(a, b); }
__device__ __forceinline__ float f32mul(float a, float b) { return __fmul_rn(a, b); }

// Wave64 argmax via DPP directional reduce; merge = (max val, min idx) == np.argmax.
__device__ __forceinline__ void waveArgmaxDpp(float& best, int& bidx) {
#define AMAX_STEP(CTRL)                                                                     \
    {                                                                                       \
        int _v = __builtin_amdgcn_update_dpp(__float_as_int(best), __float_as_int(best),    \
                                             (CTRL), 0xf, 0xf, false);                      \
        int _i = __builtin_amdgcn_update_dpp(bidx, bidx, (CTRL), 0xf, 0xf, false);          \
        float _f = __int_as_float(_v);                                                      \
        if (_f > best || (_f == best && _i < bidx)) { best = _f; bidx = _i; }               \
    }
    AMAX_STEP(0x111);  // row_shr:1
    AMAX_STEP(0x112);  // row_shr:2
    AMAX_STEP(0x114);  // row_shr:4
    AMAX_STEP(0x118);  // row_shr:8
    AMAX_STEP(0x142);  // row_bcast:15
    AMAX_STEP(0x143);  // row_bcast:31
#undef AMAX_STEP
    best = __int_as_float(__builtin_amdgcn_readlane(__float_as_int(best), 63));
    bidx = __builtin_amdgcn_readlane(bidx, 63);
}

// ---------------------------------------------------------------------------
// Kernel 1: FPS, one block (4 waves, 256 thr) per batch. PPT=16.
// Distance math bit-matches numpy-f32 (unfused, reference op order) — proven.
// 4 waves = same VALU-issue floor as 8 (4 SIMDs/CU) but half the queueing +
// cheaper barrier/merge.
// ---------------------------------------------------------------------------
__global__ __launch_bounds__(FPS_T) void fps_kernel(
    const float* __restrict__ xyz,
    int* __restrict__ fpsIdx, float* __restrict__ out0) {
    int b = blockIdx.x;
    const float* P = xyz + (size_t)b * N_ * 3;
    __shared__ float X[N_], Y[N_], Z[N_];
    __shared__ int   hist[NP_];
    __shared__ float redV[2][FPS_T / 64];
    __shared__ int   redI[2][FPS_T / 64];
    int tid = threadIdx.x;
    for (int i = tid; i < N_; i += FPS_T) {
        X[i] = P[i * 3 + 0];
        Y[i] = P[i * 3 + 1];
        Z[i] = P[i * 3 + 2];
    }
    if (tid == 0) hist[0] = 0;
    __syncthreads();

    const int PPT = N_ / FPS_T;  // 16
    float px[PPT], py[PPT], pz[PPT], dist[PPT];
#pragma unroll
    for (int c = 0; c < PPT; c++) {
        int j = tid + FPS_T * c;
        px[c] = X[j]; py[c] = Y[j]; pz[c] = Z[j];
        dist[c] = 1e10f;
    }
    int last = 0;
    for (int it = 1; it < NP_; ++it) {
        float lx = X[last], ly = Y[last], lz = Z[last];
        float best = -1.0f; int bidx = 0;
#pragma unroll
        for (int c = 0; c < PPT; c++) {
            float dx = f32sub(px[c], lx), dy = f32sub(py[c], ly), dz = f32sub(pz[c], lz);
            float nd = f32add(f32add(f32mul(dx, dx), f32mul(dy, dy)), f32mul(dz, dz));
            float d  = fminf(dist[c], nd);
            dist[c] = d;
            if (d > best) { best = d; bidx = tid + FPS_T * c; }   // ties: lowest j (c ascending)
        }
        waveArgmaxDpp(best, bidx);
        int par = it & 1;
        if ((tid & 63) == 0) { redV[par][tid >> 6] = best; redI[par][tid >> 6] = bidx; }
        __syncthreads();  // single barrier per iter; parity double-buffer makes it safe
        float bv = redV[par][0]; int bi = redI[par][0];
#pragma unroll
        for (int w = 1; w < FPS_T / 64; w++) {
            float ov = redV[par][w]; int oi = redI[par][w];
            if (ov > bv || (ov == bv && oi < bi)) { bv = ov; bi = oi; }
        }
        last = bi;
        if (tid == 0) hist[it] = last;
    }
    __syncthreads();
    for (int i = tid; i < NP_; i += FPS_T) {
        int j = hist[i];
        fpsIdx[b * NP_ + i] = j;
        size_t o = (size_t)(b * NP_ + i) * 3;
        out0[o + 0] = X[j]; out0[o + 1] = Y[j]; out0[o + 2] = Z[j];
    }
}

// ---------------------------------------------------------------------------
// Kernel 2: fused ball-query + feature_enhance + hetero_attention.
// Structure-exploiting e-GEMM: nfn has 76 columns constant in k, and the
// (fn, f-fn) / (gn*fd, g-gn*fd) pairs fold: e[k] = base + q·var[k] with only
// 69 variable cols (stored in sV[32][72]). Pooling derived per-column.
// Ball-query decision math EXACTLY as the proven round-6 kernel.
// ---------------------------------------------------------------------------
__global__ __launch_bounds__(256) void fused_kernel(
    const float* __restrict__ feat, const float* __restrict__ xyz,
    const float* __restrict__ newxyz, const int* __restrict__ fpsIdx,
    const float* __restrict__ A, const float* __restrict__ W1,
    const float* __restrict__ B1, float* __restrict__ out1) {
    int q = blockIdx.x;
    int b = q >> 10, n = q & (NP_ - 1);
    int tid = threadIdx.x;
    __shared__ float sV[K_][SVW];   // [gnf(3), dg(1), fn(64), df(1), 0,0,0]
    __shared__ float sF[68];        // f(64) ++ g(3)
    __shared__ float sFD[K_];
    __shared__ float sGD[3];
    __shared__ float sGsum[3];
    __shared__ float sPool[NC_];
    __shared__ int   sNb[K_];
    __shared__ int   sCnt;

    // ph0: f gather + g; wave 0 does ball query (proven-exact f32 math)
    if (tid < D_) sF[tid] = feat[((size_t)b * D_ + tid) * N_ + fpsIdx[q]];
    if (tid >= D_ && tid < D_ + 3) sF[tid] = newxyz[q * 3 + (tid - D_)];

    if (tid < 64) {
        int lane = tid;
        if (lane < K_) sNb[lane] = N_ - 1;   // empty-ball fallback
        const float* P = xyz + (size_t)b * N_ * 3;
        float qx = newxyz[q * 3 + 0];
        float qy = newxyz[q * 3 + 1];
        float qz = newxyz[q * 3 + 2];
        float sq = f32add(f32add(f32mul(qx, qx), f32mul(qy, qy)), f32mul(qz, qz));
        const float R2 = (float)(0.2 * 0.2);
        int count = 0;
        for (int base = 0; base < N_ && count < K_; base += 64) {
            int j = base + lane;
            float x = P[j * 3 + 0];
            float y = P[j * 3 + 1];
            float z = P[j * 3 + 2];
            float sxj = f32add(f32add(f32mul(x, x), f32mul(y, y)), f32mul(z, z));
            float dot = __fmaf_rn(qz, z, __fmaf_rn(qy, y, __fmul_rn(qx, x)));
            float d2  = f32sub(f32add(sq, sxj), f32mul(2.0f, dot));
            bool in = (d2 <= R2);
            unsigned long long m = __ballot(in);
            if (in) {
                int pos = count + __popcll(m & ((1ull << lane) - 1ull));
                if (pos < K_) sNb[pos] = j;
            }
            count += __popcll(m);
        }
        if (lane == 0) sCnt = (count < K_) ? count : K_;
    }
    __syncthreads();
    int cnt = sCnt;

    // ph1: fn -> sV[k][4..67]; raw gn -> sV[k][0..2]; zero pad cols 69..71
    {
        int k = tid >> 3, l = tid & 7;
        int j = (k < cnt || cnt == 0) ? sNb[k] : sNb[0];
        const float* src = feat + (size_t)b * D_ * N_ + j;
#pragma unroll
        for (int dd = 0; dd < 8; dd++) {
            int d = l * 8 + dd;
            sV[k][4 + d] = src[(size_t)d * N_];
        }
    }
    if (tid < 96) {
        int k = tid / 3, c = tid % 3;
        int j = (k < cnt || cnt == 0) ? sNb[k] : sNb[0];
        sV[k][c] = xyz[((size_t)b * N_ + j) * 3 + c];
        sV[k][69 + c] = 0.f;
    }
    __syncthreads();

    // ph2: fdist per neighbor (8-thread groups)
    {
        int k = tid >> 3, ds = (tid & 7) * 8;
        float s = 0.f;
#pragma unroll
        for (int j = 0; j < 8; j++) s += fabsf(sF[ds + j] - sV[k][4 + ds + j]);
        s += __shfl_xor(s, 1); s += __shfl_xor(s, 2); s += __shfl_xor(s, 4);
        if ((tid & 7) == 0) sFD[k] = __expf(-s * (1.0f / 64.0f));
    }
    __syncthreads();

    // ph3a: scale gn in place -> gnf
    if (tid < 96) {
        int k = tid / 3, c = tid % 3;
        sV[k][c] = sV[k][c] * sFD[k];
    }
    __syncthreads();

    // ph3b: dg per k; gsum per c
    if (tid < K_) {
        int k = tid;
        float a0 = sF[64] - sV[k][0], a1 = sF[65] - sV[k][1], a2 = sF[66] - sV[k][2];
        sV[k][3] = sqrtf(a0 * a0 + a1 * a1 + a2 * a2);
    }
    if (tid >= 64 && tid < 67) {
        int c = tid - 64;
        float s = 0.f;
        for (int k = 0; k < K_; k++) s += sV[k][c];
        sGsum[c] = s;
    }
    __syncthreads();

    // ph3c: gd
    if (tid == 0) {
        float m0 = sGsum[0] * (1.f / K_), m1 = sGsum[1] * (1.f / K_), m2 = sGsum[2] * (1.f / K_);
        float mm = fmaxf(m0, fmaxf(m1, m2));
        float e0 = __expf(m0 - mm), e1 = __expf(m1 - mm), e2 = __expf(m2 - mm);
        float inv = 1.f / (e0 + e1 + e2);
        float g0 = sF[64], g1 = sF[65], g2 = sF[66];
        float gm = fmaxf(g0, fmaxf(g1, g2));
        float f0 = __expf(g0 - gm), f1 = __expf(g1 - gm), f2 = __expf(g2 - gm);
        float inv2 = 1.f / (f0 + f1 + f2);
        sGD[0] = fabsf(e0 * inv - f0 * inv2);
        sGD[1] = fabsf(e1 * inv - f1 * inv2);
        sGD[2] = fabsf(e2 * inv - f2 * inv2);
    }
    __syncthreads();

    // ph4: df per k (8-thread groups over the 67 pf1 entries)
    {
        int k = tid >> 3, l = tid & 7;
        float s = 0.f;
        for (int c = l; c < 67; c += 8) {
            float v = (c < D_) ? (sF[c] - sV[k][4 + c]) : (sF[c] - sGD[c - D_]);
            s += v * v;
        }
        s += __shfl_xor(s, 1); s += __shfl_xor(s, 2); s += __shfl_xor(s, 4);
        if (l == 0) sV[k][68] = sqrtf(s);
    }
    __syncthreads();

    // ph5: e = leaky(base + q.var); softmax over k; pooled (derived per column)
    if (tid < NC_) {
        const float* Ac = A + tid;   // column tid of a, row stride NC_
        float g0 = sF[64], g1 = sF[65], g2 = sF[66];
        // base: all constant-in-k contributions
        float base = 0.f;
        base += Ac[(size_t)3 * NC_] * g0 + Ac[(size_t)4 * NC_] * g1 + Ac[(size_t)5 * NC_] * g2;
#pragma unroll 4
        for (int i = 0; i < 67; i++) base += Ac[(size_t)(77 + i) * NC_] * sF[i];
#pragma unroll
        for (int j = 0; j < 3; j++) {
            float gdj = sGD[j], gj = sF[64 + j];
            base += Ac[(size_t)(74 + j) * NC_] * gdj + Ac[(size_t)(208 + j) * NC_] * (gj - gdj);
        }
        // folded lo-rows of fn pairs into base
#pragma unroll 4
        for (int i = 0; i < D_; i++) base += Ac[(size_t)(144 + i) * NC_] * sF[i];

        float acc[K_];
#pragma unroll
        for (int k = 0; k < K_; k++) acc[k] = 0.f;

        // group 0: cols 0..3 = [gnf0..2, dg]
        {
            float q0 = Ac[0] - Ac[(size_t)6 * NC_];
            float q1 = Ac[(size_t)1 * NC_] - Ac[(size_t)7 * NC_];
            float q2 = Ac[(size_t)2 * NC_] - Ac[(size_t)8 * NC_];
            float q3 = Ac[(size_t)9 * NC_];
#pragma unroll
            for (int k = 0; k < K_; k++) {
                float4 v = *(const float4*)&sV[k][0];
                acc[k] = fmaf(v.x, q0, fmaf(v.y, q1, fmaf(v.z, q2, fmaf(v.w, q3, acc[k]))));
            }
        }
        // groups 1..16: fn cols, coef = a_hi - a_lo
        for (int gi = 0; gi < 16; gi++) {
            int i0 = gi * 4;
            float q0 = Ac[(size_t)(10 + i0 + 0) * NC_] - Ac[(size_t)(144 + i0 + 0) * NC_];
            float q1 = Ac[(size_t)(10 + i0 + 1) * NC_] - Ac[(size_t)(144 + i0 + 1) * NC_];
            float q2 = Ac[(size_t)(10 + i0 + 2) * NC_] - Ac[(size_t)(144 + i0 + 2) * NC_];
            float q3 = Ac[(size_t)(10 + i0 + 3) * NC_] - Ac[(size_t)(144 + i0 + 3) * NC_];
#pragma unroll
            for (int k = 0; k < K_; k++) {
                float4 v = *(const float4*)&sV[k][4 + i0];
                acc[k] = fmaf(v.x, q0, fmaf(v.y, q1, fmaf(v.z, q2, fmaf(v.w, q3, acc[k]))));
            }
        }
        // group 17: df col
        {
            float q0 = Ac[(size_t)211 * NC_];
#pragma unroll
            for (int k = 0; k < K_; k++) acc[k] = fmaf(sV[k][68], q0, acc[k]);
        }

        float m = -1e30f;
#pragma unroll
        for (int k = 0; k < K_; k++) {
            float v = base + acc[k];
            v = (v > 0.f) ? v : 0.2f * v;   // leaky_relu(., 0.2)
            acc[k] = v;
            m = fmaxf(m, v);
        }
        float ssum = 0.f;
#pragma unroll
        for (int k = 0; k < K_; k++) { float e = __expf(acc[k] - m); acc[k] = e; ssum += e; }
        float inv = 1.f / ssum;

        // pooled: column mapping (Σattn = 1 makes constant columns pass through)
        int col; float addv; float sgn;
        if      (tid < 3)   { col = tid;       addv = 0.f;           sgn = 1.f; }
        else if (tid < 6)   { col = 0;         addv = sF[61 + tid];  sgn = 0.f; }   // g[tid-3]
        else if (tid < 9)   { col = tid - 6;   addv = sF[58 + tid];  sgn = -1.f; }  // g - gnf
        else if (tid == 9)  { col = 3;         addv = 0.f;           sgn = 1.f; }
        else if (tid < 74)  { col = tid - 6;   addv = 0.f;           sgn = 1.f; }   // fn
        else if (tid < 77)  { col = 0;         addv = sGD[tid - 74]; sgn = 0.f; }
        else if (tid < 144) { col = 0;         addv = sF[tid - 77];  sgn = 0.f; }   // pf
        else if (tid < 208) { col = tid - 140; addv = sF[tid - 144]; sgn = -1.f; }  // f - fn
        else if (tid < 211) { col = 0;         addv = sF[tid - 144] - sGD[tid - 208]; sgn = 0.f; }
        else                { col = 68;        addv = 0.f;           sgn = 1.f; }
        float s = 0.f;
#pragma unroll
        for (int k = 0; k < K_; k++) s += acc[k] * sV[k][col];
        sPool[tid] = addv + sgn * (s * inv);
    }
    __syncthreads();

    // ph6: out = pooled @ w1^T + b1, stored transposed (B, 128, 1024) f32
    if (tid < CO_) {
        const float* w = W1 + (size_t)tid * NC_;
        float accO = 0.f;
        for (int c = 0; c < NC_; c += 4) {
            float4 wv = *(const float4*)(w + c);
            accO += wv.x * sPool[c] + wv.y * sPool[c + 1] + wv.z * sPool[c + 2] + wv.w * sPool[c + 3];
        }
        accO += B1[tid];
        out1[((size_t)b * CO_ + tid) * NP_ + n] = accO;
    }
}

// ---------------------------------------------------------------------------
extern "C" void kernel_launch(void* const* d_in, const int* in_sizes, int n_in,
                              void* d_out, int out_size, void* d_ws, size_t ws_size,
                              hipStream_t stream) {
    (void)in_sizes; (void)n_in; (void)out_size; (void)ws_size;
    const float* xyz      = (const float*)d_in[0];
    const float* features = (const float*)d_in[1];
    const float* A        = (const float*)d_in[2];
    const float* W1       = (const float*)d_in[3];
    const float* B1       = (const float*)d_in[4];
    float* out0 = (float*)d_out;                     // new_xyz (B,1024,3) f32
    float* out1 = out0 + (size_t)B_ * NP_ * 3;       // features (B,128,1024) f32

    int* fpsIdx = (int*)d_ws;                        // B*NP ints (32 KB)

    fps_kernel<<<dim3(B_), dim3(FPS_T), 0, stream>>>(xyz, fpsIdx, out0);
    fused_kernel<<<dim3(B_ * NP_), dim3(256), 0, stream>>>(features, xyz, out0, fpsIdx,
                                                           A, W1, B1, out1);
}